// Round 15
// baseline (97.386 us; speedup 1.0000x reference)
//
#include <hip/hip_runtime.h>
#include <cstdint>
#include <cstddef>

// Problem constants (from reference): N=16384, D=256.
#define NV 16384
#define DD 256
#define TPB 1024           // k_mis threads (16 waves)
#define BLK 2048           // superblock size (VPT=2)
#define OCAP 23            // pre-superblock lower-nbr cap (fallback: global row walk)
#define PCAP 7             // in-superblock lower-nbr cap (fallback: global row walk)
#define NPASS 10           // probe passes per barrier round

// compiler memory barrier: forces LDS re-reads across passes WITHOUT ordering
// the loads within a pass against each other
#define CFENCE() asm volatile("" ::: "memory")

// ---------------------------------------------------------------------------
// K_prep: per vertex v (superblock base B = v & ~2047) emit
//  - old_g[3v..3v+2] (3x uint4 = u16 slots[24]): [0]=count no, [1..23] = global
//    ids of lower nbrs j < B (these are FINAL when v's superblock runs)
//  - pend_g[v] (uint4): in-superblock lower nbrs as u16 offsets (j-B):
//      x = count | e0<<16 ; y = e1|e2<<16 ; z = e3|e4<<16 ; w = e5|e6<<16
// ---------------------------------------------------------------------------
__global__ __launch_bounds__(256)
void k_prep(const int* __restrict__ nbr, const int* __restrict__ deg,
            int maxdeg, int n, uint4* __restrict__ old_g,
            uint4* __restrict__ pend_g)
{
    int v = blockIdx.x * 256 + threadIdx.x;
    if (v >= n) return;
    const int B  = v & ~(BLK - 1);
    const int dv = deg[v];
    const int* __restrict__ row = nbr + (size_t)v * (size_t)maxdeg;
    unsigned o0=0,o1=0,o2=0,o3=0,o4=0,o5=0,o6=0,o7=0,o8=0,o9=0,o10=0,o11=0;
    unsigned w0=0,w1=0,w2=0,w3=0;
    int no = 0, np = 0;
    for (int k = 0; k < dv; ++k) {
        int j = row[k];
        if (j >= v) continue;
        if (j < B) {
            unsigned e = (unsigned)j;
            switch (no) {
                case 0:  o0 |= e << 16; break;
                case 1:  o1 |= e; break;      case 2:  o1 |= e << 16; break;
                case 3:  o2 |= e; break;      case 4:  o2 |= e << 16; break;
                case 5:  o3 |= e; break;      case 6:  o3 |= e << 16; break;
                case 7:  o4 |= e; break;      case 8:  o4 |= e << 16; break;
                case 9:  o5 |= e; break;      case 10: o5 |= e << 16; break;
                case 11: o6 |= e; break;      case 12: o6 |= e << 16; break;
                case 13: o7 |= e; break;      case 14: o7 |= e << 16; break;
                case 15: o8 |= e; break;      case 16: o8 |= e << 16; break;
                case 17: o9 |= e; break;      case 18: o9 |= e << 16; break;
                case 19: o10 |= e; break;     case 20: o10 |= e << 16; break;
                case 21: o11 |= e; break;     case 22: o11 |= e << 16; break;
                default: break;
            }
            ++no;
        } else {
            unsigned e = (unsigned)(j - B);
            switch (np) {
                case 0: w0 |= e << 16; break;
                case 1: w1 |= e; break;  case 2: w1 |= e << 16; break;
                case 3: w2 |= e; break;  case 4: w2 |= e << 16; break;
                case 5: w3 |= e; break;  case 6: w3 |= e << 16; break;
                default: break;
            }
            ++np;
        }
    }
    o0 |= (unsigned)(no > 0xffff ? 0xffff : no);
    w0 |= (unsigned)(np > 0xffff ? 0xffff : np);
    old_g[3 * (size_t)v]     = make_uint4(o0, o1, o2, o3);
    old_g[3 * (size_t)v + 1] = make_uint4(o4, o5, o6, o7);
    old_g[3 * (size_t)v + 2] = make_uint4(o8, o9, o10, o11);
    pend_g[v] = make_uint4(w0, w1, w2, w3);
}

// ---------------------------------------------------------------------------
// any head among the (FINAL) pre-superblock lower neighbors — probed ONCE.
// Groups of 8 independent LDS byte loads (bounded VGPR), group-guarded by no.
// Unused slots read st[0] (harmless; folds are count-guarded).
// ---------------------------------------------------------------------------
__device__ __forceinline__
bool any_old_head(const unsigned char* st, uint4 A, uint4 Bw, uint4 Cw, int no,
                  int V, int B, const int* __restrict__ nbr,
                  const int* __restrict__ deg, int maxdeg)
{
    if (no > OCAP) {            // rare: walk global row (statuses final)
        const int dv = deg[V];
        const int* __restrict__ row = nbr + (size_t)V * (size_t)maxdeg;
        bool a = false;
        for (int k = 0; k < dv; ++k) { int j = row[k]; if (j < B) a |= (st[j] == 1); }
        return a;
    }
    bool a;
    {
        int q0 = st[A.x >> 16],      q1 = st[A.y & 0xffffu], q2 = st[A.y >> 16];
        int q3 = st[A.z & 0xffffu],  q4 = st[A.z >> 16],     q5 = st[A.w & 0xffffu];
        int q6 = st[A.w >> 16],      q7 = st[Bw.x & 0xffffu];
        a = (no > 0 && q0 == 1) || (no > 1 && q1 == 1) || (no > 2 && q2 == 1)
         || (no > 3 && q3 == 1) || (no > 4 && q4 == 1) || (no > 5 && q5 == 1)
         || (no > 6 && q6 == 1) || (no > 7 && q7 == 1);
    }
    if (no > 8) {
        int q8  = st[Bw.x >> 16],     q9  = st[Bw.y & 0xffffu], q10 = st[Bw.y >> 16];
        int q11 = st[Bw.z & 0xffffu], q12 = st[Bw.z >> 16],     q13 = st[Bw.w & 0xffffu];
        int q14 = st[Bw.w >> 16],     q15 = st[Cw.x & 0xffffu];
        a = a || (q8 == 1) || (no > 9 && q9 == 1) || (no > 10 && q10 == 1)
              || (no > 11 && q11 == 1) || (no > 12 && q12 == 1)
              || (no > 13 && q13 == 1) || (no > 14 && q14 == 1)
              || (no > 15 && q15 == 1);
    }
    if (no > 16) {
        int q16 = st[Cw.x >> 16],     q17 = st[Cw.y & 0xffffu], q18 = st[Cw.y >> 16];
        int q19 = st[Cw.z & 0xffffu], q20 = st[Cw.z >> 16],     q21 = st[Cw.w & 0xffffu];
        int q22 = st[Cw.w >> 16];
        a = a || (q16 == 1) || (no > 17 && q17 == 1) || (no > 18 && q18 == 1)
              || (no > 19 && q19 == 1) || (no > 20 && q20 == 1)
              || (no > 21 && q21 == 1) || (no > 22 && q22 == 1);
    }
    return a;
}

// decide from in-superblock pend probes (only called while my==0)
__device__ __forceinline__
void pend_decide(int& my, unsigned char* st, int V, int B, uint4 P, int np,
                 int dvf, const int* __restrict__ nbr, int maxdeg)
{
    bool anyH = false; int undec = 0;
    if (np <= PCAP) {
        int q0 = st[B + (P.x >> 16)],      q1 = st[B + (P.y & 0xffffu)];
        int q2 = st[B + (P.y >> 16)],      q3 = st[B + (P.z & 0xffffu)];
        int q4 = st[B + (P.z >> 16)],      q5 = st[B + (P.w & 0xffffu)];
        int q6 = st[B + (P.w >> 16)];
        if (np > 0) { anyH |= (q0 == 1); undec += (q0 == 0); }
        if (np > 1) { anyH |= (q1 == 1); undec += (q1 == 0); }
        if (np > 2) { anyH |= (q2 == 1); undec += (q2 == 0); }
        if (np > 3) { anyH |= (q3 == 1); undec += (q3 == 0); }
        if (np > 4) { anyH |= (q4 == 1); undec += (q4 == 0); }
        if (np > 5) { anyH |= (q5 == 1); undec += (q5 == 0); }
        if (np > 6) { anyH |= (q6 == 1); undec += (q6 == 0); }
    } else {                    // rare: walk global row for in-superblock lowers
        const int* __restrict__ row = nbr + (size_t)V * (size_t)maxdeg;
        for (int k = 0; k < dvf; ++k) {
            int j = row[k];
            if (j >= B && j < V) { int q = st[j]; anyH |= (q == 1); undec += (q == 0); }
        }
    }
    if (anyH)            { my = 2; st[V] = 2; }
    else if (undec == 0) { my = 1; st[V] = 1; }
}

// ---------------------------------------------------------------------------
// K_mis: lexicographic greedy MIS, single WG of 1024 threads (16 waves),
// PURE PULL, minimal-DS design. st: 0=unknown,1=head,2=nonhead; each vertex
// writes ONLY its own byte. Per superblock of 2048 (v0=b+t, v1=b+1024+t):
//   STEP A (once): probe the FINAL pre-superblock lower nbrs -> decided
//     immediately if any head found or no in-superblock deps.
//   Rounds: only UNDECIDED lanes probe their <=7 in-superblock pend slots
//     (loads inside the my==0 guard -> near-zero DS traffic once decided),
//     fence between passes, ballot early-exit, drain-free barrier per round.
// No pushes, no own-status reads: total DS instructions ~= one edge sweep.
// ---------------------------------------------------------------------------
__global__ __launch_bounds__(TPB, 4)
void k_mis(const int* __restrict__ nbr, const int* __restrict__ deg,
           int maxdeg, int n,
           const uint4* __restrict__ old_g, const uint4* __restrict__ pend_g,
           int* __restrict__ headlist, float* __restrict__ out_tail)
{
    __shared__ __align__(16) unsigned char st[NV];
    __shared__ int s_ws[TPB / 64];
    __shared__ int F[3];
    const int t    = threadIdx.x;
    const int lane = t & 63;
    const int wid  = t >> 6;

    ((uint4*)st)[t] = make_uint4(0u, 0u, 0u, 0u);   // 1024*16B == NV
    if (t < 3) F[t] = 0;
    __syncthreads();

    // current superblock records (2 vertices/thread), double-buffered
    uint4 a0A = make_uint4(0,0,0,0), a0B = a0A, a0C = a0A, p0 = a0A;
    uint4 a1A = a0A, a1B = a0A, a1C = a0A, p1 = a0A;
    {
        int v0 = t, v1 = 1024 + t;
        if (v0 < n) {
            a0A = old_g[3*(size_t)v0]; a0B = old_g[3*(size_t)v0+1];
            a0C = old_g[3*(size_t)v0+2]; p0 = pend_g[v0];
        }
        if (v1 < n) {
            a1A = old_g[3*(size_t)v1]; a1B = old_g[3*(size_t)v1+1];
            a1C = old_g[3*(size_t)v1+2]; p1 = pend_g[v1];
        }
    }
    int r = 0;

    for (int b = 0; b < n; b += BLK) {
        const int v0 = b + t, v1 = b + 1024 + t;
        // prefetch next superblock; stays in flight across drain-free barriers
        uint4 s0A = make_uint4(0,0,0,0), s0B = s0A, s0C = s0A, q0 = s0A;
        uint4 s1A = s0A, s1B = s0A, s1C = s0A, q1 = s0A;
        {
            int w0 = b + BLK + t, w1 = b + BLK + 1024 + t;
            if (w0 < n) {
                s0A = old_g[3*(size_t)w0]; s0B = old_g[3*(size_t)w0+1];
                s0C = old_g[3*(size_t)w0+2]; q0 = pend_g[w0];
            }
            if (w1 < n) {
                s1A = old_g[3*(size_t)w1]; s1B = old_g[3*(size_t)w1+1];
                s1C = old_g[3*(size_t)w1+2]; q1 = pend_g[w1];
            }
        }

        const int no0 = (int)(a0A.x & 0xffffu), np0 = (int)(p0.x & 0xffffu);
        const int no1 = (int)(a1A.x & 0xffffu), np1 = (int)(p1.x & 0xffffu);

        int my0 = (v0 < n) ? 0 : 2;
        int my1 = (v1 < n) ? 0 : 2;
        int dvf0 = 0, dvf1 = 0;
        if (my0 == 0 && np0 > PCAP) dvf0 = deg[v0];
        if (my1 == 0 && np1 > PCAP) dvf1 = deg[v1];

        // ---- STEP A: fold the FINAL pre-superblock neighbors (once) ----
        if (my0 == 0) {
            bool aH = any_old_head(st, a0A, a0B, a0C, no0, v0, b, nbr, deg, maxdeg);
            if (aH)            { my0 = 2; st[v0] = 2; }
            else if (np0 == 0) { my0 = 1; st[v0] = 1; }
        }
        if (my1 == 0) {
            bool aH = any_old_head(st, a1A, a1B, a1C, no1, v1, b, nbr, deg, maxdeg);
            if (aH)            { my1 = 2; st[v1] = 2; }
            else if (np1 == 0) { my1 = 1; st[v1] = 1; }
        }

        // ---- rounds: only undecided lanes probe their pend slots ----
        for (;; ++r) {
            if (t == 0) F[(r + 1) % 3] = 0;
            for (int pass = 0; pass < NPASS; ++pass) {
                if (my0 == 0) pend_decide(my0, st, v0, b, p0, np0, dvf0, nbr, maxdeg);
                if (my1 == 0) pend_decide(my1, st, v1, b, p1, np1, dvf1, nbr, maxdeg);
                if (__ballot((my0 == 0) || (my1 == 0)) == 0ULL) break;
                CFENCE();   // force genuine LDS re-reads next pass
            }
            if ((my0 == 0) || (my1 == 0)) F[r % 3] = 1;
            // drain-free barrier: LDS visible, global prefetch stays in flight
            asm volatile("s_waitcnt lgkmcnt(0)\n\ts_barrier" ::: "memory");
            if (F[r % 3] == 0) { ++r; break; }
        }
        a0A = s0A; a0B = s0B; a0C = s0C; p0 = q0;
        a1A = s1A; a1B = s1B; a1C = s1C; p1 = q1;
    }

    // ---- epilogue: count heads, scan, emit headlist / head_mask / count ----
    uint4 qq = ((const uint4*)st)[t];          // thread t owns bytes [16t,16t+16)
    int cnt = __popc(qq.x & 0x01010101u) + __popc(qq.y & 0x01010101u)
            + __popc(qq.z & 0x01010101u) + __popc(qq.w & 0x01010101u);
    int c = cnt;
    #pragma unroll
    for (int off = 1; off < 64; off <<= 1) {
        int x = __shfl_up(c, off);
        if (lane >= off) c += x;
    }
    if (lane == 63) s_ws[wid] = c;
    __syncthreads();
    int wexcl = 0, tot = 0;
    #pragma unroll
    for (int w = 0; w < TPB / 64; ++w) {
        int s = s_ws[w];
        tot += s;
        if (w < wid) wexcl += s;
    }
    int excl = wexcl + (c - cnt);
    #pragma unroll
    for (int i = 0; i < 16; ++i) {
        int v = t * 16 + i;
        if (st[v] == 1) { headlist[excl] = v; ++excl; }
    }
    for (int i = t; i < NV / 4; i += TPB) {
        unsigned w = ((const unsigned*)st)[i];
        float4 f;
        f.x = (float)(w & 1u);         f.y = (float)((w >> 8) & 1u);
        f.z = (float)((w >> 16) & 1u); f.w = (float)((w >> 24) & 1u);
        ((float4*)out_tail)[i] = f;
    }
    if (t == 0) out_tail[n] = (float)tot;
}

// ---------------------------------------------------------------------------
// K_avg (fused owner+avg): one 64-lane wave per output row.
// Waves [0,tot): cluster mean for h=headlist[w]. Candidate j in row(h) is a
// member iff j nonhead AND min{head nbrs of j} == h (walk j's row in-lane;
// j<h auto-excluded since its min head nbr < j < h).
// Waves [tot,n): zero-fill the row (replaces the memset).
// ---------------------------------------------------------------------------
__global__ __launch_bounds__(256)
void k_avg(const float* __restrict__ vert, const int* __restrict__ nbr,
           const int* __restrict__ deg, int maxdeg, int n,
           const int* __restrict__ headlist,
           const float* __restrict__ tail, float* __restrict__ out)
{
    const int w    = (blockIdx.x * 256 + threadIdx.x) >> 6;
    const int lane = threadIdx.x & 63;
    if (w >= n) return;
    const int tot  = (int)tail[n];
    if (w >= tot) {
        reinterpret_cast<float4*>(out + (size_t)w * DD)[lane] = make_float4(0.f, 0.f, 0.f, 0.f);
        return;
    }
    const int h = headlist[w];

    const int dh = deg[h];
    const int* __restrict__ row = nbr + (size_t)h * (size_t)maxdeg;

    float4 acc = reinterpret_cast<const float4*>(vert + (size_t)h * DD)[lane];
    int cnt = 1;

    for (int k0 = 0; k0 < dh; k0 += 64) {
        int k = k0 + lane;
        int j = (k < dh) ? row[k] : -1;
        bool mem = false;
        if (j > h && tail[j] == 0.0f) {        // nonhead, higher candidate
            const int dj = deg[j];
            const int* __restrict__ rj = nbr + (size_t)j * (size_t)maxdeg;
            int mn = 0x7fffffff;
            for (int kk = 0; kk < dj; ++kk) {
                int u = rj[kk];
                if (tail[u] != 0.0f) mn = min(mn, u);
            }
            mem = (mn == h);
        }
        unsigned long long m = __ballot(mem);
        cnt += __popcll(m);
        while (m) {
            int bit = __ffsll((long long)m) - 1;
            m &= (m - 1);
            int jj = __shfl(j, bit);
            float4 rr = reinterpret_cast<const float4*>(vert + (size_t)jj * DD)[lane];
            acc.x += rr.x; acc.y += rr.y; acc.z += rr.z; acc.w += rr.w;
        }
    }
    const float inv = 1.0f / (float)cnt;
    float4 res;
    res.x = acc.x * inv; res.y = acc.y * inv;
    res.z = acc.z * inv; res.w = acc.w * inv;
    reinterpret_cast<float4*>(out + (size_t)w * DD)[lane] = res;
}

// ---------------------------------------------------------------------------
extern "C" void kernel_launch(void* const* d_in, const int* in_sizes, int n_in,
                              void* d_out, int out_size, void* d_ws, size_t ws_size,
                              hipStream_t stream)
{
    const float* vert = (const float*)d_in[0];
    const int*   nbr  = (const int*)d_in[1];
    const int*   deg  = (const int*)d_in[2];

    const int n      = in_sizes[2];            // 16384
    const int maxdeg = in_sizes[1] / n;
    const int d      = in_sizes[0] / n;        // 256

    int*   headlist = (int*)d_ws;                                  // n ints
    uint4* pend_g   = (uint4*)(headlist + n);                      // n uint4 (256KB)
    uint4* old_g    = pend_g + n;                                  // 3n uint4 (768KB)

    float* out      = (float*)d_out;
    float* out_tail = out + (size_t)n * (size_t)d;   // head_mask .. num_clusters

    hipLaunchKernelGGL(k_prep, dim3((n + 255) / 256), dim3(256), 0, stream,
                       nbr, deg, maxdeg, n, old_g, pend_g);

    hipLaunchKernelGGL(k_mis, dim3(1), dim3(TPB), 0, stream,
                       nbr, deg, maxdeg, n, old_g, pend_g, headlist, out_tail);

    const int blocks = (n * 64 + 255) / 256;   // one wave per output row
    hipLaunchKernelGGL(k_avg, dim3(blocks), dim3(256), 0, stream,
                       vert, nbr, deg, maxdeg, n, headlist, out_tail, out);
}